// Round 9
// baseline (38.785 us; speedup 1.0000x reference)
//
#include <hip/hip_runtime.h>
#include <float.h>

// ROI max-pool via sliding-4-max pyramid, WG-count-minimized version.
//   S4x[y][x]  = max fm[y][x..x+3]   (indices clamped at edge)
//   S4y[y][x]  = max fm[y..y+3][x]
//   S4xy[y][x] = max fm[y..y+3][x..x+3]
// Build: 512 WGs; block = (b, x, y-quarter), loops 4 y-bands with mod-7 LDS
// row rotation (only 4 new rows per band).
// Query: 832 WGs of 512 threads; each wave owns 4 bins of ONE roi (13 waves
// per roi, slots 49..51 clamp to bin 48 -> duplicate identical stores).
// Bin range (len<=15) covered by <=4 overlapping spans/dim (last at e-4;
// overlap free under fmax); len in {2,3} -> singles.
// Reference semantics:
//   h0=(int)(H*r0); h1=(int)(H*r2); step=(h1-h0)/7
//   bin i<6: [h0+i*step, h0+(i+1)*step); bin 6: [h0+6*step, h1)
//   step==0 -> all valid pixels in bin 6; empty bin -> -FLT_MAX
constexpr int H = 64, W = 64, C = 256, PH = 7, PW = 7;

typedef float f32x4 __attribute__((ext_vector_type(4)));

__device__ __forceinline__ f32x4 vmax4(f32x4 a, f32x4 b) {
    f32x4 r;
    r.x = fmaxf(a.x, b.x); r.y = fmaxf(a.y, b.y);
    r.z = fmaxf(a.z, b.z); r.w = fmaxf(a.w, b.w);
    return r;
}

// ---- build: grid = B * W * 4 quarters = 512 blocks of 256 ----
__global__ __launch_bounds__(256) void build_tables(
    const float* __restrict__ fm, float* __restrict__ s4x,
    float* __restrict__ s4y, float* __restrict__ s4xy)
{
    __shared__ f32x4 lfm[7][64];   // logical row L lives in slot L%7
    __shared__ f32x4 lsx[7][64];

    const int lane = threadIdx.x & 63;
    const int wave = __builtin_amdgcn_readfirstlane(threadIdx.x >> 6); // 0..3

    const int b = blockIdx.x & 1;                  // batch -> XCD parity
    const int p = blockIdx.x >> 1;                 // 0..255
    const int x = p & (W - 1);
    const int k0 = (p >> 6) << 2;                  // starting band: 0,4,8,12

    const int x1 = min(x + 1, W - 1), x2 = min(x + 2, W - 1), x3 = min(x + 3, W - 1);
    const float* fmb = fm + (size_t)b * H * W * C + (size_t)lane * 4;

    auto loadrow = [&](int L) {                    // logical row L -> slot L%7
        const int y = min(L, H - 1);               // clamp == table edge rule
        const float* row = fmb + (size_t)y * W * C;
        f32x4 v0 = *(const f32x4*)(row + (size_t)x  * C);
        f32x4 v1 = *(const f32x4*)(row + (size_t)x1 * C);
        f32x4 v2 = *(const f32x4*)(row + (size_t)x2 * C);
        f32x4 v3 = *(const f32x4*)(row + (size_t)x3 * C);
        lfm[L % 7][lane] = v0;
        lsx[L % 7][lane] = vmax4(vmax4(v0, v1), vmax4(v2, v3));
    };

    // initial 7 rows for band k0: L = 4k0 .. 4k0+6
    loadrow(4 * k0 + wave);
    if (wave < 3) loadrow(4 * k0 + 4 + wave);
    __syncthreads();

    for (int k = k0; ; ++k) {
        const int y = 4 * k + wave;                // output row (<= 63 always)
        const f32x4 sx  = lsx[y % 7][lane];
        const f32x4 sy  = vmax4(vmax4(lfm[y % 7][lane], lfm[(y + 1) % 7][lane]),
                                vmax4(lfm[(y + 2) % 7][lane], lfm[(y + 3) % 7][lane]));
        const f32x4 sxy = vmax4(vmax4(lsx[y % 7][lane], lsx[(y + 1) % 7][lane]),
                                vmax4(lsx[(y + 2) % 7][lane], lsx[(y + 3) % 7][lane]));

        const size_t o = ((size_t)(b * H + y) * W + x) * C + (size_t)lane * 4;
        __builtin_nontemporal_store(sx, reinterpret_cast<f32x4*>(s4x + o));
        __builtin_nontemporal_store(sy, reinterpret_cast<f32x4*>(s4y + o));
        *(f32x4*)(s4xy + o) = sxy;                 // hot table: keep cacheable

        if (k == k0 + 3) break;
        __syncthreads();                           // readers done before overwrite
        loadrow(4 * (k + 1) + 3 + wave);           // 4 new rows for band k+1
        __syncthreads();
    }
}

// ---- query: 512-thr blocks; wave = 4 bins of one roi ----
__global__ __launch_bounds__(512) void roi_pool_q(
    const float* __restrict__ fm, const float* __restrict__ rois,
    const float* __restrict__ s4x, const float* __restrict__ s4y,
    const float* __restrict__ s4xy, float* __restrict__ out, int R)
{
    const int lane = threadIdx.x & 63;
    const int wave = __builtin_amdgcn_readfirstlane(threadIdx.x >> 6); // 0..7

    const int b = blockIdx.x & 1;                  // batch -> XCD parity
    const int q = blockIdx.x >> 1;                 // 0..415
    const int gw = q * 8 + wave;                   // 0..3327
    const int r  = gw / 13;                        // roi (magic-mul)
    const int c  = gw - 13 * r;                    // chunk 0..12

    const f32x4 rv = *(const f32x4*)(rois + ((size_t)b * R + r) * 4);
    int h0 = (int)((float)H * rv.x);               // trunc == astype(int32)
    int w0 = (int)((float)W * rv.y);
    int h1 = (int)((float)H * rv.z);
    int w1 = (int)((float)W * rv.w);
    h0 = __builtin_amdgcn_readfirstlane(h0);
    w0 = __builtin_amdgcn_readfirstlane(w0);
    h1 = __builtin_amdgcn_readfirstlane(h1);
    w1 = __builtin_amdgcn_readfirstlane(w1);
    const int hs = (h1 - h0) / PH;
    const int ws = (w1 - w0) / PW;

    const size_t img = (size_t)b * H * W * C;
    const float* fmb   = fm   + img + lane * 4;
    const float* s4xb  = s4x  + img + lane * 4;
    const float* s4yb  = s4y  + img + lane * 4;
    const float* s4xyb = s4xy + img + lane * 4;
    const size_t obase = (((size_t)b * R + r) * PH * PW) * C + (size_t)lane * 4;

    #pragma unroll
    for (int t = 0; t < 4; ++t) {
        const int id = min(c * 4 + t, PH * PW - 1);    // clamp dup of bin 48
        const int i = id / PW;                          // uniform
        const int j = id - PW * i;

        int ys, ye, xs, xe;
        if (hs > 0) { ys = h0 + i * hs; ye = (i < PH - 1) ? (ys + hs) : h1; }
        else        { ys = h0;          ye = (i == PH - 1) ? h1 : h0; }
        if (ws > 0) { xs = w0 + j * ws; xe = (j < PW - 1) ? (xs + ws) : w1; }
        else        { xs = w0;          xe = (j == PW - 1) ? w1 : w0; }
        ys = __builtin_amdgcn_readfirstlane(max(ys, 0));
        ye = __builtin_amdgcn_readfirstlane(min(ye, H));
        xs = __builtin_amdgcn_readfirstlane(max(xs, 0));
        xe = __builtin_amdgcn_readfirstlane(min(xe, W));

        const int hl = ye - ys, wl = xe - xs;
        const f32x4 NEG = {-FLT_MAX, -FLT_MAX, -FLT_MAX, -FLT_MAX};
        f32x4 a0 = NEG, a1 = NEG, a2 = NEG, a3 = NEG;

        if (hl > 0 && wl > 0) {
            const bool y4 = hl >= 4, x4 = wl >= 4;
            const int ny = y4 ? (hl + 3) >> 2 : hl;    // <= 4
            const int nx = x4 ? (wl + 3) >> 2 : wl;    // <= 4
            const int ystep = y4 ? 4 : 1, xstep = x4 ? 4 : 1;
            const int ycl = y4 ? ye - 4 : ye - 1;
            const int xcl = x4 ? xe - 4 : xe - 1;
            const float* tbb = y4 ? (x4 ? s4xyb : s4yb) : (x4 ? s4xb : fmb);

            const int xo0 = min(xs,             xcl) * C;
            const int xo1 = min(xs + xstep,     xcl) * C;
            const int xo2 = min(xs + 2 * xstep, xcl) * C;
            const int xo3 = min(xs + 3 * xstep, xcl) * C;

            #pragma unroll
            for (int ky = 0; ky < 4; ++ky) {
                if (ky < ny) {                          // wave-uniform guard
                    const int y = min(ys + ystep * ky, ycl);
                    const float* rowp = tbb + (size_t)y * (W * C);
                    a0 = vmax4(a0, *(const f32x4*)(rowp + xo0));
                    if (nx > 1) a1 = vmax4(a1, *(const f32x4*)(rowp + xo1));
                    if (nx > 2) a2 = vmax4(a2, *(const f32x4*)(rowp + xo2));
                    if (nx > 3) a3 = vmax4(a3, *(const f32x4*)(rowp + xo3));
                }
            }
        }
        const f32x4 acc = vmax4(vmax4(a0, a1), vmax4(a2, a3));
        __builtin_nontemporal_store(acc,
            reinterpret_cast<f32x4*>(out + obase + (size_t)id * C));
    }
}

// ---- verified fallback (R5 kernel) if ws too small ----
__global__ __launch_bounds__(256) void roi_pool_direct(
    const float* __restrict__ fm, const float* __restrict__ rois,
    float* __restrict__ out, int R)
{
    const int lane = threadIdx.x & 63;
    const int wave = __builtin_amdgcn_readfirstlane(threadIdx.x >> 6);
    const int b = blockIdx.x & 1;
    int m = (blockIdx.x >> 1) * 4 + wave;
    int j = m % PW; m /= PW;
    int i = m % PH; m /= PH;
    int r = m;

    const float* roi = rois + ((size_t)b * R + r) * 4;
    int h0 = (int)((float)H * roi[0]);
    int w0 = (int)((float)W * roi[1]);
    int h1 = (int)((float)H * roi[2]);
    int w1 = (int)((float)W * roi[3]);
    int hs = (h1 - h0) / PH;
    int ws = (w1 - w0) / PW;

    int ys, ye, xs, xe;
    if (hs > 0) { ys = h0 + i * hs; ye = (i < PH - 1) ? (ys + hs) : h1; }
    else        { ys = h0;          ye = (i == PH - 1) ? h1 : h0; }
    if (ws > 0) { xs = w0 + j * ws; xe = (j < PW - 1) ? (xs + ws) : w1; }
    else        { xs = w0;          xe = (j == PW - 1) ? w1 : w0; }
    ys = __builtin_amdgcn_readfirstlane(max(ys, 0));
    ye = __builtin_amdgcn_readfirstlane(min(ye, H));
    xs = __builtin_amdgcn_readfirstlane(max(xs, 0));
    xe = __builtin_amdgcn_readfirstlane(min(xe, W));

    const f32x4 NEG = {-FLT_MAX, -FLT_MAX, -FLT_MAX, -FLT_MAX};
    f32x4 a0 = NEG, a1 = NEG, a2 = NEG, a3 = NEG;
    const float* fmb = fm + (size_t)b * (H * W * C);
    const int lo = lane * 4;

    for (int y = ys; y < ye; y += 2) {
        const int y1 = min(y + 1, ye - 1);
        const int ro0 = y  * (W * C);
        const int ro1 = y1 * (W * C);
        for (int x = xs; x < xe; x += 2) {
            const int x1 = min(x + 1, xe - 1);
            a0 = vmax4(a0, *(const f32x4*)(fmb + ro0 + x  * C + lo));
            a1 = vmax4(a1, *(const f32x4*)(fmb + ro0 + x1 * C + lo));
            a2 = vmax4(a2, *(const f32x4*)(fmb + ro1 + x  * C + lo));
            a3 = vmax4(a3, *(const f32x4*)(fmb + ro1 + x1 * C + lo));
        }
    }
    f32x4 acc = vmax4(vmax4(a0, a1), vmax4(a2, a3));
    size_t o = ((((size_t)b * R + r) * PH + i) * PW + j) * C + (size_t)lo;
    __builtin_nontemporal_store(acc, reinterpret_cast<f32x4*>(out + o));
}

extern "C" void kernel_launch(void* const* d_in, const int* in_sizes, int n_in,
                              void* d_out, int out_size, void* d_ws, size_t ws_size,
                              hipStream_t stream) {
    const float* fm   = (const float*)d_in[0];
    const float* rois = (const float*)d_in[1];
    float* out = (float*)d_out;

    const int B = in_sizes[0] / (H * W * C);        // = 2
    const int R = in_sizes[1] / (B * 4);            // = 256

    const size_t tbl = (size_t)B * H * W * C;       // floats per table
    const size_t need = 3 * tbl * sizeof(float);    // 24 MB for B=2

    if (B == 2 && R == 256 && ws_size >= need) {
        float* s4x  = (float*)d_ws;
        float* s4y  = s4x + tbl;
        float* s4xy = s4y + tbl;
        const int bblocks = B * W * 4;              // 512
        const int qblocks = B * (R * 13 / 8) * 2 / 2; // 832 (2 imgs x 416)
        build_tables<<<bblocks, 256, 0, stream>>>(fm, s4x, s4y, s4xy);
        roi_pool_q  <<<qblocks, 512, 0, stream>>>(fm, rois, s4x, s4y, s4xy, out, R);
    } else {
        const int qblocks = B * (R * PH * PW / 4);
        roi_pool_direct<<<qblocks, 256, 0, stream>>>(fm, rois, out, R);
    }
}

// Round 10
// 24.295 us; speedup vs baseline: 1.5964x; 1.5964x over previous
//
#include <hip/hip_runtime.h>
#include <float.h>

// ROI max-pool via sliding-4-max pyramid, XCD-locality version.
//   S4x[y][x]  = max fm[y][x..x+3]   (indices clamped at edge)
//   S4y[y][x]  = max fm[y..y+3][x]
//   S4xy[y][x] = max fm[y..y+3][x..x+3]
// Query blocks are partitioned over XCDs by bin-row i (XCD slot = b*4 + g,
// g: i-pairs {0,1},{2,3},{4,5},{6}) so each XCD's table slice (~2.5-3.5 MB)
// fits its 4 MiB L2 — avoids the cross-XCD LLC round-trip that limited R8.
// Query: bin range (len<=15) covered by <=4 overlapping spans/dim (last span
// at e-4; overlap free under fmax); len in {2,3} -> singles.
// Reference semantics:
//   h0=(int)(H*r0); h1=(int)(H*r2); step=(h1-h0)/7
//   bin i<6: [h0+i*step, h0+(i+1)*step); bin 6: [h0+6*step, h1)
//   step==0 -> all valid pixels in bin 6; empty bin -> -FLT_MAX
constexpr int H = 64, W = 64, C = 256, PH = 7, PW = 7;

typedef float f32x4 __attribute__((ext_vector_type(4)));

__device__ __forceinline__ f32x4 vmax4(f32x4 a, f32x4 b) {
    f32x4 r;
    r.x = fmaxf(a.x, b.x); r.y = fmaxf(a.y, b.y);
    r.z = fmaxf(a.z, b.z); r.w = fmaxf(a.w, b.w);
    return r;
}

// ---- fused build: 2048 blocks; blockIdx%8 = b*4 + y-quartile ----
__global__ __launch_bounds__(256) void build_tables(
    const float* __restrict__ fm, float* __restrict__ s4x,
    float* __restrict__ s4y, float* __restrict__ s4xy)
{
    __shared__ f32x4 lds_fm[7][64];    // fm[y0+k][x] channel quads
    __shared__ f32x4 lds_sx[7][64];    // s4x[y0+k][x]

    const int lane = threadIdx.x & 63;
    const int wave = __builtin_amdgcn_readfirstlane(threadIdx.x >> 6); // 0..3

    const int x8 = blockIdx.x & 7;
    const int z  = blockIdx.x >> 3;                  // 0..255
    const int b  = x8 >> 2;                          // batch
    const int quart = x8 & 3;                        // y-quartile -> same XCD as its queries
    const int x  = z & (W - 1);
    const int y0 = quart * 16 + ((z >> 6) << 2);     // 4-row band

    const int x1 = min(x + 1, W - 1), x2 = min(x + 2, W - 1), x3 = min(x + 3, W - 1);
    const float* fmb = fm + (size_t)b * H * W * C + (size_t)lane * 4;

    // wave w owns halo slots {w} and (w<3 ? {4+w} : {})
    #pragma unroll
    for (int s = 0; s < 2; ++s) {
        const int slot = wave + 4 * s;
        if (slot < 7) {
            const int y = min(y0 + slot, H - 1);     // clamp == table edge rule
            const float* row = fmb + (size_t)y * W * C;
            f32x4 v0 = *(const f32x4*)(row + (size_t)x  * C);
            f32x4 v1 = *(const f32x4*)(row + (size_t)x1 * C);
            f32x4 v2 = *(const f32x4*)(row + (size_t)x2 * C);
            f32x4 v3 = *(const f32x4*)(row + (size_t)x3 * C);
            lds_fm[slot][lane] = v0;
            lds_sx[slot][lane] = vmax4(vmax4(v0, v1), vmax4(v2, v3));
        }
    }
    __syncthreads();

    const int y = y0 + wave;
    const f32x4 sx = lds_sx[wave][lane];
    const f32x4 sy = vmax4(vmax4(lds_fm[wave][lane],     lds_fm[wave + 1][lane]),
                           vmax4(lds_fm[wave + 2][lane], lds_fm[wave + 3][lane]));
    const f32x4 sxy = vmax4(vmax4(lds_sx[wave][lane],     lds_sx[wave + 1][lane]),
                            vmax4(lds_sx[wave + 2][lane], lds_sx[wave + 3][lane]));

    const size_t o = ((size_t)(b * H + y) * W + x) * C + (size_t)lane * 4;
    *(f32x4*)(s4x  + o) = sx;
    *(f32x4*)(s4y  + o) = sy;
    *(f32x4*)(s4xy + o) = sxy;
}

// ---- query: 7168 blocks; blockIdx%8 = b*4 + i-group ----
__global__ __launch_bounds__(256) void roi_pool_q(
    const float* __restrict__ fm, const float* __restrict__ rois,
    const float* __restrict__ s4x, const float* __restrict__ s4y,
    const float* __restrict__ s4xy, float* __restrict__ out, int R)
{
    const int lane = threadIdx.x & 63;
    const int wave = __builtin_amdgcn_readfirstlane(threadIdx.x >> 6);

    const int x8 = blockIdx.x & 7;                   // XCD slot
    const int n  = blockIdx.x >> 3;                  // [0, 896)
    const int b  = x8 >> 2;                          // batch
    const int g  = x8 & 3;                           // i-group {0,1},{2,3},{4,5},{6}

    int i, id;
    if (g < 3) {
        i  = 2 * g + (n & 1);
        id = (n >> 1) * 4 + wave;                    // [0, 1792)
    } else {
        if (n >= 448) return;                        // pad blocks: idle
        i  = 6;
        id = n * 4 + wave;
    }
    const int r = id / 7;                            // roi
    const int j = id - 7 * r;                        // col bin

    const float* roi = rois + ((size_t)b * R + r) * 4;
    int h0 = (int)((float)H * roi[0]);               // trunc == astype(int32)
    int w0 = (int)((float)W * roi[1]);
    int h1 = (int)((float)H * roi[2]);
    int w1 = (int)((float)W * roi[3]);
    int hs = (h1 - h0) / PH;
    int ws = (w1 - w0) / PW;

    int ys, ye, xs, xe;
    if (hs > 0) { ys = h0 + i * hs; ye = (i < PH - 1) ? (ys + hs) : h1; }
    else        { ys = h0;          ye = (i == PH - 1) ? h1 : h0; }
    if (ws > 0) { xs = w0 + j * ws; xe = (j < PW - 1) ? (xs + ws) : w1; }
    else        { xs = w0;          xe = (j == PW - 1) ? w1 : w0; }
    ys = __builtin_amdgcn_readfirstlane(max(ys, 0));
    ye = __builtin_amdgcn_readfirstlane(min(ye, H));
    xs = __builtin_amdgcn_readfirstlane(max(xs, 0));
    xe = __builtin_amdgcn_readfirstlane(min(xe, W));

    const int hl = ye - ys, wl = xe - xs;
    const f32x4 NEG = {-FLT_MAX, -FLT_MAX, -FLT_MAX, -FLT_MAX};
    f32x4 a0 = NEG, a1 = NEG, a2 = NEG, a3 = NEG;   // per-kx-slot accumulators

    if (hl > 0 && wl > 0) {
        // bin length <= 15 always -> <=4 spans per dim
        const bool y4 = hl >= 4, x4 = wl >= 4;
        const int ny = y4 ? (hl + 3) >> 2 : hl;     // <= 4
        const int nx = x4 ? (wl + 3) >> 2 : wl;     // <= 4
        const int ystep = y4 ? 4 : 1, xstep = x4 ? 4 : 1;
        const int ycl = y4 ? ye - 4 : ye - 1;
        const int xcl = x4 ? xe - 4 : xe - 1;
        const float* tb = y4 ? (x4 ? s4xy : s4y) : (x4 ? s4x : fm);
        const float* tbb = tb + (size_t)b * H * W * C + lane * 4;

        // x-span byte offsets (uniform)
        const int xo0 = min(xs,             xcl) * C;
        const int xo1 = min(xs + xstep,     xcl) * C;
        const int xo2 = min(xs + 2 * xstep, xcl) * C;
        const int xo3 = min(xs + 3 * xstep, xcl) * C;

        #pragma unroll
        for (int ky = 0; ky < 4; ++ky) {
            if (ky < ny) {                           // wave-uniform guard
                const int y = min(ys + ystep * ky, ycl);
                const float* rowp = tbb + (size_t)y * (W * C);
                a0 = vmax4(a0, *(const f32x4*)(rowp + xo0));
                if (nx > 1) a1 = vmax4(a1, *(const f32x4*)(rowp + xo1));
                if (nx > 2) a2 = vmax4(a2, *(const f32x4*)(rowp + xo2));
                if (nx > 3) a3 = vmax4(a3, *(const f32x4*)(rowp + xo3));
            }
        }
    }
    const f32x4 acc = vmax4(vmax4(a0, a1), vmax4(a2, a3));

    size_t o = ((((size_t)b * R + r) * PH + i) * PW + j) * C + (size_t)lane * 4;
    __builtin_nontemporal_store(acc, reinterpret_cast<f32x4*>(out + o));
}

// ---- verified fallback (R5 kernel) if ws too small ----
__global__ __launch_bounds__(256) void roi_pool_direct(
    const float* __restrict__ fm, const float* __restrict__ rois,
    float* __restrict__ out, int R)
{
    const int lane = threadIdx.x & 63;
    const int wave = __builtin_amdgcn_readfirstlane(threadIdx.x >> 6);
    const int b = blockIdx.x & 1;
    int m = (blockIdx.x >> 1) * 4 + wave;
    int j = m % PW; m /= PW;
    int i = m % PH; m /= PH;
    int r = m;

    const float* roi = rois + ((size_t)b * R + r) * 4;
    int h0 = (int)((float)H * roi[0]);
    int w0 = (int)((float)W * roi[1]);
    int h1 = (int)((float)H * roi[2]);
    int w1 = (int)((float)W * roi[3]);
    int hs = (h1 - h0) / PH;
    int ws = (w1 - w0) / PW;

    int ys, ye, xs, xe;
    if (hs > 0) { ys = h0 + i * hs; ye = (i < PH - 1) ? (ys + hs) : h1; }
    else        { ys = h0;          ye = (i == PH - 1) ? h1 : h0; }
    if (ws > 0) { xs = w0 + j * ws; xe = (j < PW - 1) ? (xs + ws) : w1; }
    else        { xs = w0;          xe = (j == PW - 1) ? w1 : w0; }
    ys = __builtin_amdgcn_readfirstlane(max(ys, 0));
    ye = __builtin_amdgcn_readfirstlane(min(ye, H));
    xs = __builtin_amdgcn_readfirstlane(max(xs, 0));
    xe = __builtin_amdgcn_readfirstlane(min(xe, W));

    const f32x4 NEG = {-FLT_MAX, -FLT_MAX, -FLT_MAX, -FLT_MAX};
    f32x4 a0 = NEG, a1 = NEG, a2 = NEG, a3 = NEG;
    const float* fmb = fm + (size_t)b * (H * W * C);
    const int lo = lane * 4;

    for (int y = ys; y < ye; y += 2) {
        const int y1 = min(y + 1, ye - 1);
        const int ro0 = y  * (W * C);
        const int ro1 = y1 * (W * C);
        for (int x = xs; x < xe; x += 2) {
            const int x1 = min(x + 1, xe - 1);
            a0 = vmax4(a0, *(const f32x4*)(fmb + ro0 + x  * C + lo));
            a1 = vmax4(a1, *(const f32x4*)(fmb + ro0 + x1 * C + lo));
            a2 = vmax4(a2, *(const f32x4*)(fmb + ro1 + x  * C + lo));
            a3 = vmax4(a3, *(const f32x4*)(fmb + ro1 + x1 * C + lo));
        }
    }
    f32x4 acc = vmax4(vmax4(a0, a1), vmax4(a2, a3));
    size_t o = ((((size_t)b * R + r) * PH + i) * PW + j) * C + (size_t)lo;
    __builtin_nontemporal_store(acc, reinterpret_cast<f32x4*>(out + o));
}

extern "C" void kernel_launch(void* const* d_in, const int* in_sizes, int n_in,
                              void* d_out, int out_size, void* d_ws, size_t ws_size,
                              hipStream_t stream) {
    const float* fm   = (const float*)d_in[0];
    const float* rois = (const float*)d_in[1];
    float* out = (float*)d_out;

    const int B = in_sizes[0] / (H * W * C);        // = 2
    const int R = in_sizes[1] / (B * 4);            // = 256

    const size_t tbl = (size_t)B * H * W * C;       // floats per table
    const size_t need = 3 * tbl * sizeof(float);    // 24 MB for B=2

    if (B == 2 && R == 256 && ws_size >= need) {
        float* s4x  = (float*)d_ws;
        float* s4y  = s4x + tbl;
        float* s4xy = s4y + tbl;
        build_tables<<<2048, 256, 0, stream>>>(fm, s4x, s4y, s4xy);
        roi_pool_q  <<<7168, 256, 0, stream>>>(fm, rois, s4x, s4y, s4xy, out, R);
    } else {
        const int qblocks = B * (R * PH * PW / 4);
        roi_pool_direct<<<qblocks, 256, 0, stream>>>(fm, rois, out, R);
    }
}